// Round 2
// baseline (693.711 us; speedup 1.0000x reference)
//
#include <hip/hip_runtime.h>

// Wave equation velocity-Verlet, 23x23 periodic grid, 2 components (x, v).
// One block per batch element; position field double-buffered in LDS.
// Reuses a2(step n) as a1(step n+1) -> one Laplacian per step.
//
// Round-2 change: producer/consumer wave specialization. Round-1 showed the
// per-step global store is serialized into the compute critical path even
// without the barrier's vmcnt drain (WAR on the reused store-data VGPRs
// forces a per-iteration vmcnt wait ~store-ack latency). Fix structurally:
// compute waves (9) never issue global stores in the loop; they deposit
// (xn, vn) into a double-buffered LDS ring. A dedicated writer wave (wave 9)
// drains the ring to global with coalesced 8B/lane stores, one step behind.
// Writer stalls only on vmcnt-full (= chip write-BW saturated), which is the
// write roofline (~415 cy/step/CU), not on per-store latency.

#define S 23
#define CELLS (S * S)     // 529
#define NCOMP 576         // compute threads (9 waves), >= CELLS
#define NT 640            // + 1 writer wave

// LDS-only workgroup barrier: orders ds ops across waves without draining
// outstanding global stores (vmcnt).
__device__ __forceinline__ void lds_barrier() {
    asm volatile("s_waitcnt lgkmcnt(0)" ::: "memory");
    __builtin_amdgcn_s_barrier();
    asm volatile("" ::: "memory");
}

__global__ __launch_bounds__(NT, 1)
void wave_step_kernel(const float* __restrict__ y0,
                      const float* __restrict__ dt_p,
                      const int* __restrict__ nsteps_p,
                      const int* __restrict__ inc_p,
                      float* __restrict__ out)
{
    const int b = blockIdx.x;
    const int c = threadIdx.x;

    const float dt = *dt_p;
    const int nsteps = *nsteps_p;
    const int inc = *inc_p;

    const float c2 = 9.0f;              // WAVE_SPEED^2
    const float half_dt = 0.5f * dt;
    const float half_dt2 = 0.5f * dt * dt;

    __shared__ float  xs[2][CELLS];     // position field, double-buffered
    __shared__ float2 ring[2][CELLS];   // (x, v) output ring, double-buffered

    const int T = nsteps + (inc ? 1 : 0);
    const float2* y0v = (const float2*)y0 + (size_t)b * CELLS;
    float2* outv = (float2*)out + (size_t)b * T * CELLS;
    float2* outt = outv + (inc ? CELLS : 0);   // row pointer for step outputs

    const bool writer = (c >= NCOMP);
    const bool active = (c < CELLS);

    float x = 0.0f, v = 0.0f, a = 0.0f;
    int iL = 0, iR = 0, iU = 0, iD = 0;

    if (active) {
        float2 xv = y0v[c];             // interleaved (position, velocity)
        x = xv.x;
        v = xv.y;
        int i = c / S;
        int j = c - i * S;
        iL = i * S + (j == 0 ? S - 1 : j - 1);
        iR = i * S + (j == S - 1 ? 0 : j + 1);
        iU = (i == 0 ? S - 1 : i - 1) * S + j;
        iD = (i == S - 1 ? 0 : i + 1) * S + j;
        xs[0][c] = x;
        if (inc) outv[c] = xv;          // t=0 row is y0 itself (one-time store)
    }
    lds_barrier();

    if (active) {
        a = c2 * (xs[0][iL] + xs[0][iR] + xs[0][iU] + xs[0][iD] - 4.0f * x);
    }

    const int wlane = c - NCOMP;        // writer lane 0..63
    int buf = 0;

    for (int t = 0; t < nsteps; ++t) {
        const int nbuf = buf ^ 1;
        float xn = 0.0f;
        if (active) {
            xn = x + v * dt + a * half_dt2;
            xs[nbuf][c] = xn;
        }
        lds_barrier();                  // xs[nbuf] ready; ring[buf] (step t-1) sealed
        if (active) {
            const float* xb = xs[nbuf];
            float an = c2 * (xb[iL] + xb[iR] + xb[iU] + xb[iD] - 4.0f * xn);
            float vn = v + (a + an) * half_dt;
            float2 o;
            o.x = xn;
            o.y = vn;
            ring[nbuf][c] = o;          // hand off to writer wave (drained at t+1)
            x = xn;
            v = vn;
            a = an;
        } else if (writer && t > 0) {
            // Drain step t-1's output: 529 float2, coalesced 512B/instr.
            const float2* rb = ring[buf];
            float2* orow = outt + (size_t)(t - 1) * CELLS;
            #pragma unroll
            for (int k = 0; k < 9; ++k) {
                int idx = k * 64 + wlane;
                if (idx < CELLS) orow[idx] = rb[idx];
            }
        }
        buf ^= 1;
    }

    // Drain the final step's output.
    lds_barrier();
    if (writer && nsteps > 0) {
        const float2* rb = ring[buf];
        float2* orow = outt + (size_t)(nsteps - 1) * CELLS;
        #pragma unroll
        for (int k = 0; k < 9; ++k) {
            int idx = k * 64 + wlane;
            if (idx < CELLS) orow[idx] = rb[idx];
        }
    }
}

extern "C" void kernel_launch(void* const* d_in, const int* in_sizes, int n_in,
                              void* d_out, int out_size, void* d_ws, size_t ws_size,
                              hipStream_t stream) {
    const float* y0 = (const float*)d_in[0];
    const float* dt_p = (const float*)d_in[1];
    const int* nsteps_p = (const int*)d_in[2];
    const int* inc_p = (const int*)d_in[3];
    float* out = (float*)d_out;

    const int B = in_sizes[0] / (CELLS * 2);   // 256

    wave_step_kernel<<<B, NT, 0, stream>>>(y0, dt_p, nsteps_p, inc_p, out);
}